// Round 3
// baseline (479.875 us; speedup 1.0000x reference)
//
#include <hip/hip_runtime.h>

// YOLO loss, MI355X. pred [256, 2704, 9, 5] fp32 (124.6 MB) -> scalar.
// Floors: memory ~20us (124.6MB @ 6.3TB/s; less w/ LLC reuse), VALU ~15-25us.
//
// Round-2 lesson: 2028 blocks x 15-deep serial load/compute chains =
// latency-bound (VALUBusy 20%, BW 1TB/s, occupancy 19%, 124us). This round:
//  - 7605 blocks (exact: 7605*1024 float4 = 7,787,520), each owns a
//    CONTIGUOUS 16KB chunk -> L2/XCD locality, 3.75x TLP.
//  - each thread issues 4 independent coalesced float4 loads into registers
//    (lane stride 16B within each instr), THEN computes: depth-4 MLP.
//  - __launch_bounds__(256,8): cap VGPR at 64 -> 8 waves/SIMD residency.
//  - per-float branchless channel math (c=F%5, a=(F/5)%9), one exp + one rcp.
//  - 2 launches; last-finished block does the final combine.
//
// ws layout (floats):
//  [0] coor_sq_obj  [1] conf_sq_obj  [2] coor_obj(label)  [3] conf_obj(iou)
//  [4 .. 4+256)        coor buckets (atomic)
//  [4+256 .. 4+512)    conf buckets (atomic)
//  [516]               completion counter (as int)

#define GHW     52
#define GCELLS  2704          // 52*52
#define NA      9
#define BATCH   256
#define NBLK    (GCELLS * NA) // 24336 elements/sample; NBLK*BATCH = 6,230,016
#define INV52   (1.0f / 52.0f)
#define NBUCKET 256
#define CNT_IDX (4 + 2 * NBUCKET)

#define NQ4     7787520u      // total float4s = 31,150,080 floats / 4 (exact)
#define DEPTH   4             // float4 loads in flight per thread
#define NB2     7605          // grid; 7605 * 256 * 4 == 7,787,520 exactly

__device__ __forceinline__ float sigmoid_exact(float x) {
    return 1.0f / (1.0f + __expf(-x));      // IEEE div; only in tiny obj kernel
}

__device__ __forceinline__ float waveReduceSum(float v) {
#pragma unroll
    for (int o = 32; o > 0; o >>= 1) v += __shfl_down(v, o, 64);
    return v;
}

// ---------------- Kernel A: per-sample responsible box, IoU, obj sums -------
// Also zero-inits buckets + counter (replaces a hipMemsetAsync launch).
__global__ __launch_bounds__(256) void yolo_obj_kernel(
        const float* __restrict__ pred,
        const float* __restrict__ label,
        const float* __restrict__ anchors,
        float* __restrict__ ws) {
    __shared__ float anch[18];
    __shared__ float red[4][4];
    int b = threadIdx.x;

    // zero accumulator region for the noobj kernel (stream order => visible)
    ws[4 + b] = 0.0f;
    ws[4 + NBUCKET + b] = 0.0f;
    if (b == 0) ((int*)ws)[CNT_IDX] = 0;

    if (b < 18) anch[b] = anchors[b];
    __syncthreads();

    float4 lab = ((const float4*)label)[b];
    float lx = lab.x, ly = lab.y, lw = lab.z, lh = lab.w;

    int ix = (int)floorf(lx * 52.0f);
    int iy = (int)floorf(ly * 52.0f);
    int idx = ix * GHW + iy;

    // argmax over anchors of squared distance (first-max, strict >)
    int am = 0; float best = -1.0f;
#pragma unroll
    for (int a = 0; a < NA; ++a) {
        float dw = lw - anch[2 * a];
        float dh = lh - anch[2 * a + 1];
        float d = dw * dw + dh * dh;
        if (d > best) { best = d; am = a; }
    }

    const float* p = pred + (((size_t)b * GCELLS + idx) * NA + am) * 5;
    float v0 = p[0], v1 = p[1], v2 = p[2], v3 = p[3], v4 = p[4];

    float aw = anch[2 * am], ah = anch[2 * am + 1];
    float px = (sigmoid_exact(v0) + (float)ix) * INV52;
    float py = (sigmoid_exact(v1) + (float)iy) * INV52;
    float pw = aw * __expf(v2);
    float ph = ah * __expf(v3);
    float pc = sigmoid_exact(v4);

    float agx = ((float)ix + 0.5f) * INV52;
    float agy = ((float)iy + 0.5f) * INV52;

    float d0 = px - agx, d1 = py - agy, d2 = pw - aw, d3 = ph - ah;
    float coor_sq_obj = d0 * d0 + d1 * d1 + d2 * d2 + d3 * d3;
    float conf_sq_obj = pc * pc;

    float e0 = px - lx, e1 = py - ly, e2 = pw - lw, e3 = ph - lh;
    float coor_obj = e0 * e0 + e1 * e1 + e2 * e2 + e3 * e3;

    // IoU (faithful: areas = x2*y2, not (x2-x1)*(y2-y1))
    float lx1 = fmaxf(lx - lw * 0.5f, 0.0f), ly1 = fmaxf(ly - lh * 0.5f, 0.0f);
    float lx2 = fminf(lx + lw * 0.5f, 1.0f), ly2 = fminf(ly + lh * 0.5f, 1.0f);
    float qx1 = fmaxf(px - pw * 0.5f, 0.0f), qy1 = fmaxf(py - ph * 0.5f, 0.0f);
    float qx2 = fminf(px + pw * 0.5f, 1.0f), qy2 = fminf(py + ph * 0.5f, 1.0f);
    float ix1 = fmaxf(lx1, qx1), iy1 = fmaxf(ly1, qy1);
    float ix2 = fminf(lx2, qx2), iy2 = fminf(ly2, qy2);
    float la = lx2 * ly2, pa = qx2 * qy2;
    float inter = fmaxf(ix2 - ix1, 0.0f) * fmaxf(iy2 - iy1, 0.0f);
    float iou = inter / (la + pa - inter);
    float dcf = pc - iou;
    float conf_obj = dcf * dcf;

    float r0 = waveReduceSum(coor_sq_obj);
    float r1 = waveReduceSum(conf_sq_obj);
    float r2 = waveReduceSum(coor_obj);
    float r3 = waveReduceSum(conf_obj);
    int lane = threadIdx.x & 63, wid = threadIdx.x >> 6;
    if (lane == 0) {
        red[0][wid] = r0; red[1][wid] = r1; red[2][wid] = r2; red[3][wid] = r3;
    }
    __syncthreads();
    if (threadIdx.x < 4) {
        ws[threadIdx.x] = red[threadIdx.x][0] + red[threadIdx.x][1]
                        + red[threadIdx.x][2] + red[threadIdx.x][3];
    }
}

// ---------------- Kernel B: noobj reduction (124.6 MB pass) + final combine -
// Block owns 1024 consecutive float4s (16KB). Thread t loads float4s
// {base+t, base+256+t, base+512+t, base+768+t} back-to-back (all coalesced,
// all in flight), then computes. Per-float branchless channel math.
__global__ __launch_bounds__(256, 8) void yolo_noobj_kernel(
        const float* __restrict__ pred,
        const float* __restrict__ anchors,
        float* __restrict__ ws,
        float* __restrict__ out) {
    __shared__ float anch[18];
    __shared__ float red[2][4];
    __shared__ int isLast;
    int t = threadIdx.x;
    if (t < 18) anch[t] = anchors[t];
    __syncthreads();

    const float4* __restrict__ g4 = (const float4*)pred;
    unsigned qbase = (unsigned)blockIdx.x * (256u * DEPTH) + (unsigned)t;

    // issue all DEPTH loads before any use
    float4 A[DEPTH];
#pragma unroll
    for (int j = 0; j < DEPTH; ++j) A[j] = g4[qbase + (unsigned)j * 256u];

    float coorAcc = 0.0f, confAcc = 0.0f;
#pragma unroll
    for (int j = 0; j < DEPTH; ++j) {
        float xs[4] = {A[j].x, A[j].y, A[j].z, A[j].w};
        unsigned q  = qbase + (unsigned)j * 256u;
        unsigned F0 = q * 4u;                      // flat float index, < 2^25
        unsigned e  = F0 / 5u;                     // const-div -> magic mul
        unsigned c  = F0 - 5u * e;                 // channel 0..4
        unsigned a  = e % 9u;                      // anchor 0..8

#pragma unroll
        for (int k = 0; k < 4; ++k) {
            float x = xs[k];
            bool isWH = (c == 2u) | (c == 3u);
            float u = __expf(isWH ? x : -x);               // one transcendental
            float s = __builtin_amdgcn_rcpf(1.0f + u);     // sigmoid (~1 ulp)
            float aval = anch[2u * a + (c & 1u)];          // idx in [0,17]
            float d = isWH ? (aval * (u - 1.0f))           // pred_wh - anchor_wh
                           : ((s - 0.5f) * INV52);         // pred_xy - grid_xy
            bool isConf = (c == 4u);
            coorAcc += isConf ? 0.0f : d * d;
            confAcc += isConf ? s * s : 0.0f;
            ++c;
            if (c == 5u) { c = 0u; a = (a == 8u) ? 0u : a + 1u; }
        }
    }

    float rc = waveReduceSum(coorAcc);
    float rf = waveReduceSum(confAcc);
    int lane = t & 63, wid = t >> 6;
    if (lane == 0) { red[0][wid] = rc; red[1][wid] = rf; }
    __syncthreads();
    if (t == 0) {
        float cs = red[0][0] + red[0][1] + red[0][2] + red[0][3];
        float fs = red[1][0] + red[1][1] + red[1][2] + red[1][3];
        int bk = blockIdx.x & (NBUCKET - 1);       // ~30 blocks/bucket
        atomicAdd(&ws[4 + bk], cs);
        atomicAdd(&ws[4 + NBUCKET + bk], fs);
        __threadfence();                           // buckets visible before counter
        int old = atomicAdd((int*)ws + CNT_IDX, 1);
        isLast = (old == NB2 - 1);
    }
    __syncthreads();

    if (isLast) {
        // all buckets complete; read via device-scope atomics (cross-XCD safe)
        float c = atomicAdd(&ws[4 + t], 0.0f);
        float f = atomicAdd(&ws[4 + NBUCKET + t], 0.0f);
        float rc2 = waveReduceSum(c);
        float rf2 = waveReduceSum(f);
        if (lane == 0) { red[0][wid] = rc2; red[1][wid] = rf2; }
        __syncthreads();
        if (t == 0) {
            float coor_all = red[0][0] + red[0][1] + red[0][2] + red[0][3];
            float conf_all = red[1][0] + red[1][1] + red[1][2] + red[1][3];
            // ws[0..3] written by yolo_obj_kernel (prior dispatch, coherent)
            float coor_l_noobj = (coor_all - ws[0]) / (float)(BATCH * (NBLK - 1) * 4);
            float conf_l_noobj = (conf_all - ws[1]) / (float)(BATCH * (NBLK - 1));
            float coor_l_obj = ws[2] / (float)(BATCH * 4);
            float conf_l_obj = ws[3] / (float)BATCH;
            out[0] = coor_l_obj + coor_l_noobj + conf_l_obj + conf_l_noobj;
        }
    }
}

extern "C" void kernel_launch(void* const* d_in, const int* in_sizes, int n_in,
                              void* d_out, int out_size, void* d_ws, size_t ws_size,
                              hipStream_t stream) {
    const float* pred    = (const float*)d_in[0];
    const float* label   = (const float*)d_in[1];
    const float* anchors = (const float*)d_in[2];
    float* out = (float*)d_out;
    float* ws  = (float*)d_ws;

    yolo_obj_kernel<<<1, 256, 0, stream>>>(pred, label, anchors, ws);
    yolo_noobj_kernel<<<NB2, 256, 0, stream>>>(pred, anchors, ws, out);
}

// Round 4
// 182.879 us; speedup vs baseline: 2.6240x; 2.6240x over previous
//
#include <hip/hip_runtime.h>

// YOLO loss, MI355X. pred [256, 2704, 9, 5] fp32 (124.6 MB) -> scalar.
//
// Empirical record for the big (noobj) pass:
//   R0 (prev session): 24336 blk, LDS-staged coalesced f4, no fence, 4 dispatches
//       -> ~55us implied (187 total - ~130 fixed fill/launch overhead). BEST.
//   R1 80B-stride regs:        192us (uncoalesced)
//   R2 grid-stride deep-serial: 125us (latency-bound, 19% occ)
//   R3 depth-4 regs + launch_bounds(256,8): 328us (compiler dropped MLP;
//       fused-fin __threadfence (L2 writeback per block) common to R1-R3)
// => revert to R0 structure; levers: 512 elem/block (2x per-wave MLP),
//    rcp sigmoid (bit-exact, absmax 0.0 in R1-R3), init fused into kernel A,
//    NO fence / NO counter in the hot kernel; separate tiny fin dispatch.
//
// ws layout (floats):
//  [0] coor_sq_obj  [1] conf_sq_obj  [2] coor_obj(label)  [3] conf_obj(iou)
//  [4 .. 4+256)        coor buckets (atomic)
//  [4+256 .. 4+512)    conf buckets (atomic)

#define GHW     52
#define GCELLS  2704          // 52*52
#define NA      9
#define BATCH   256
#define NBLK    (GCELLS * NA) // 24336 elements/sample; NBLK*BATCH = 6,230,016
#define INV52   (1.0f / 52.0f)
#define NBUCKET 256

#define ELEMS_B 512                       // elements per block
#define NB2     12168                     // 6,230,016 / 512 exactly
#define Q4_B    640                       // float4s per block = 512*5/4

__device__ __forceinline__ float sigmoid_exact(float x) {
    return 1.0f / (1.0f + __expf(-x));    // IEEE div; only in tiny obj kernel
}

__device__ __forceinline__ float sigmoid_fast(float x) {
    return __builtin_amdgcn_rcpf(1.0f + __expf(-x));  // ~1 ulp; absmax 0.0 so far
}

__device__ __forceinline__ float waveReduceSum(float v) {
#pragma unroll
    for (int o = 32; o > 0; o >>= 1) v += __shfl_down(v, o, 64);
    return v;
}

// ---------------- Kernel A: per-sample responsible box, IoU, obj sums -------
// Also zero-inits the bucket region (stream order makes it visible to B).
__global__ __launch_bounds__(256) void yolo_obj_kernel(
        const float* __restrict__ pred,
        const float* __restrict__ label,
        const float* __restrict__ anchors,
        float* __restrict__ ws) {
    __shared__ float anch[18];
    __shared__ float red[4][4];
    int b = threadIdx.x;

    ws[4 + b] = 0.0f;
    ws[4 + NBUCKET + b] = 0.0f;

    if (b < 18) anch[b] = anchors[b];
    __syncthreads();

    float4 lab = ((const float4*)label)[b];
    float lx = lab.x, ly = lab.y, lw = lab.z, lh = lab.w;

    int ix = (int)floorf(lx * 52.0f);
    int iy = (int)floorf(ly * 52.0f);
    int idx = ix * GHW + iy;

    // argmax over anchors of squared distance (first-max, strict >)
    int am = 0; float best = -1.0f;
#pragma unroll
    for (int a = 0; a < NA; ++a) {
        float dw = lw - anch[2 * a];
        float dh = lh - anch[2 * a + 1];
        float d = dw * dw + dh * dh;
        if (d > best) { best = d; am = a; }
    }

    const float* p = pred + (((size_t)b * GCELLS + idx) * NA + am) * 5;
    float v0 = p[0], v1 = p[1], v2 = p[2], v3 = p[3], v4 = p[4];

    float aw = anch[2 * am], ah = anch[2 * am + 1];
    float px = (sigmoid_exact(v0) + (float)ix) * INV52;
    float py = (sigmoid_exact(v1) + (float)iy) * INV52;
    float pw = aw * __expf(v2);
    float ph = ah * __expf(v3);
    float pc = sigmoid_exact(v4);

    float agx = ((float)ix + 0.5f) * INV52;
    float agy = ((float)iy + 0.5f) * INV52;

    float d0 = px - agx, d1 = py - agy, d2 = pw - aw, d3 = ph - ah;
    float coor_sq_obj = d0 * d0 + d1 * d1 + d2 * d2 + d3 * d3;
    float conf_sq_obj = pc * pc;

    float e0 = px - lx, e1 = py - ly, e2 = pw - lw, e3 = ph - lh;
    float coor_obj = e0 * e0 + e1 * e1 + e2 * e2 + e3 * e3;

    // IoU (faithful: areas = x2*y2, not (x2-x1)*(y2-y1))
    float lx1 = fmaxf(lx - lw * 0.5f, 0.0f), ly1 = fmaxf(ly - lh * 0.5f, 0.0f);
    float lx2 = fminf(lx + lw * 0.5f, 1.0f), ly2 = fminf(ly + lh * 0.5f, 1.0f);
    float qx1 = fmaxf(px - pw * 0.5f, 0.0f), qy1 = fmaxf(py - ph * 0.5f, 0.0f);
    float qx2 = fminf(px + pw * 0.5f, 1.0f), qy2 = fminf(py + ph * 0.5f, 1.0f);
    float ix1 = fmaxf(lx1, qx1), iy1 = fmaxf(ly1, qy1);
    float ix2 = fminf(lx2, qx2), iy2 = fminf(ly2, qy2);
    float la = lx2 * ly2, pa = qx2 * qy2;
    float inter = fmaxf(ix2 - ix1, 0.0f) * fmaxf(iy2 - iy1, 0.0f);
    float iou = inter / (la + pa - inter);
    float dcf = pc - iou;
    float conf_obj = dcf * dcf;

    float r0 = waveReduceSum(coor_sq_obj);
    float r1 = waveReduceSum(conf_sq_obj);
    float r2 = waveReduceSum(coor_obj);
    float r3 = waveReduceSum(conf_obj);
    int lane = threadIdx.x & 63, wid = threadIdx.x >> 6;
    if (lane == 0) {
        red[0][wid] = r0; red[1][wid] = r1; red[2][wid] = r2; red[3][wid] = r3;
    }
    __syncthreads();
    if (threadIdx.x < 4) {
        ws[threadIdx.x] = red[threadIdx.x][0] + red[threadIdx.x][1]
                        + red[threadIdx.x][2] + red[threadIdx.x][3];
    }
}

// ---------------- Kernel B: noobj reduction (124.6 MB pass) -----------------
// R0 structure, doubled: block stages 512 elements (2560 floats = 640 float4
// = 10KB) via coalesced float4, threads then each process 2 elements from LDS
// (stride-5 reads: 2-way bank aliasing = free). No fence, no counter.
__global__ __launch_bounds__(256) void yolo_noobj_kernel(
        const float* __restrict__ pred,
        const float* __restrict__ anchors,
        float* __restrict__ ws) {
    __shared__ float sh[ELEMS_B * 5];   // 2560 floats = 10KB
    __shared__ float anch[18];
    __shared__ float red[2][4];
    int t = threadIdx.x;

    // stage 640 float4s, perfectly coalesced; 2-3 loads in flight per thread
    size_t f0 = (size_t)blockIdx.x * Q4_B;
    const float4* __restrict__ g4 = (const float4*)pred;
    ((float4*)sh)[t]       = g4[f0 + t];
    ((float4*)sh)[t + 256] = g4[f0 + 256 + t];
    if (t < 128) ((float4*)sh)[t + 512] = g4[f0 + 512 + t];
    if (t < 18) anch[t] = anchors[t];
    __syncthreads();

    float coorAcc = 0.0f, confAcc = 0.0f;
#pragma unroll
    for (int h = 0; h < 2; ++h) {
        int le = t + h * 256;                       // local element 0..511
        int e  = blockIdx.x * ELEMS_B + le;         // global element < 6.23M
        int a  = e % NA;
        float aw = anch[2 * a], ah = anch[2 * a + 1];

        const float* m = sh + 5 * le;               // stride-5: 2-way (free)
        float v0 = m[0], v1 = m[1], v2 = m[2], v3 = m[3], v4 = m[4];

        float s0 = sigmoid_fast(v0);
        float s1 = sigmoid_fast(v1);
        float s4 = sigmoid_fast(v4);
        float t0 = (s0 - 0.5f) * INV52;             // == pred_x - anchors_grid_x
        float t1 = (s1 - 0.5f) * INV52;
        float t2 = aw * (__expf(v2) - 1.0f);        // == pred_w - anchor_w
        float t3 = ah * (__expf(v3) - 1.0f);

        coorAcc += t0 * t0 + t1 * t1 + t2 * t2 + t3 * t3;
        confAcc += s4 * s4;
    }

    float rc = waveReduceSum(coorAcc);
    float rf = waveReduceSum(confAcc);
    int lane = t & 63, wid = t >> 6;
    if (lane == 0) { red[0][wid] = rc; red[1][wid] = rf; }
    __syncthreads();
    if (t == 0) {
        float cs = red[0][0] + red[0][1] + red[0][2] + red[0][3];
        float fs = red[1][0] + red[1][1] + red[1][2] + red[1][3];
        int bk = blockIdx.x & (NBUCKET - 1);        // ~48 blocks/bucket
        atomicAdd(&ws[4 + bk], cs);
        atomicAdd(&ws[4 + NBUCKET + bk], fs);
    }
}

// ---------------- Kernel C: bucket reduce + final combine -------------------
__global__ __launch_bounds__(256) void yolo_fin_kernel(
        const float* __restrict__ ws,
        float* __restrict__ out) {
    __shared__ float red[2][4];
    int t = threadIdx.x;
    float c = ws[4 + t];
    float f = ws[4 + NBUCKET + t];
    float rc = waveReduceSum(c);
    float rf = waveReduceSum(f);
    int lane = t & 63, wid = t >> 6;
    if (lane == 0) { red[0][wid] = rc; red[1][wid] = rf; }
    __syncthreads();
    if (t == 0) {
        float coor_all = red[0][0] + red[0][1] + red[0][2] + red[0][3];
        float conf_all = red[1][0] + red[1][1] + red[1][2] + red[1][3];
        float coor_l_noobj = (coor_all - ws[0]) / (float)(BATCH * (NBLK - 1) * 4);
        float conf_l_noobj = (conf_all - ws[1]) / (float)(BATCH * (NBLK - 1));
        float coor_l_obj = ws[2] / (float)(BATCH * 4);
        float conf_l_obj = ws[3] / (float)BATCH;
        out[0] = coor_l_obj + coor_l_noobj + conf_l_obj + conf_l_noobj;
    }
}

extern "C" void kernel_launch(void* const* d_in, const int* in_sizes, int n_in,
                              void* d_out, int out_size, void* d_ws, size_t ws_size,
                              hipStream_t stream) {
    const float* pred    = (const float*)d_in[0];
    const float* label   = (const float*)d_in[1];
    const float* anchors = (const float*)d_in[2];
    float* out = (float*)d_out;
    float* ws  = (float*)d_ws;

    yolo_obj_kernel<<<1, 256, 0, stream>>>(pred, label, anchors, ws);
    yolo_noobj_kernel<<<NB2, 256, 0, stream>>>(pred, anchors, ws);
    yolo_fin_kernel<<<1, 256, 0, stream>>>(ws, out);
}